// Round 2
// baseline (2563.865 us; speedup 1.0000x reference)
//
#include <hip/hip_runtime.h>

// ---------------------------------------------------------------------------
// DendriticMLP on MI355X — round 2.
// All GEMMs: fp32 operands staged to LDS as f16 hi/lo planes (in-register
// split during staging), 3-term MFMA (hh+hl+lh) => ~2^-22 relative error,
// fp32-grade, so the 25M discrete decisions (abs-max gating, top-k) match
// the fp32 reference. Workspace: 96 MB (gates 32 + y 32 + h 32), no
// precomputed planes, no global_load_lds (crash-risk isolation).
// ---------------------------------------------------------------------------

typedef _Float16 f16x8 __attribute__((ext_vector_type(8)));
typedef _Float16 f16x4 __attribute__((ext_vector_type(4)));
typedef float    f32x4 __attribute__((ext_vector_type(4)));

// Stage a [rows x 32]-float tile (row-major, leading dim ld, col offset kcol)
// into two LDS f16 planes [rows][32] (hi + lo), splitting in registers.
// rows*8 float4-chunks, strided over 256 threads.
__device__ __forceinline__ void stage_split(const float* __restrict__ g, long row0,
                                            int ld, int kcol, _Float16* sH,
                                            _Float16* sL, int rows, int tid) {
    const int chunks = rows << 3;  // 8 float4 per row
    for (int c = tid; c < chunks; c += 256) {
        const float4 v =
            *(const float4*)(g + (long)(row0 + (c >> 3)) * ld + kcol + ((c & 7) << 2));
        f16x4 h, l;
        h.x = (_Float16)v.x; l.x = (_Float16)(v.x - (float)h.x);
        h.y = (_Float16)v.y; l.y = (_Float16)(v.y - (float)h.y);
        h.z = (_Float16)v.z; l.z = (_Float16)(v.z - (float)h.z);
        h.w = (_Float16)v.w; l.w = (_Float16)(v.w - (float)h.w);
        const int off = c << 2;  // element offset = row*32 + (c&7)*4 = c*4
        *(f16x4*)(sH + off) = h;
        *(f16x4*)(sL + off) = l;
    }
}

// ---------------------------------------------------------------------------
// Split-f16 GEMM: C[M,N] = A[M,K] @ B[N,K]^T + bias[N]; A,B fp32 in global.
// 128x128 tile, 4 waves 2x2, each wave 64x64 via 4x4 of 16x16x32_f16 MFMA,
// 3 MFMAs per fragment pair (hh + hl + lh; ll term ~2^-22, dropped).
// ---------------------------------------------------------------------------
__global__ __launch_bounds__(256) void gemm_split(
    const float* __restrict__ A, const float* __restrict__ B,
    const float* __restrict__ bias, float* __restrict__ C, int N, int K) {
    __shared__ __align__(16) _Float16 sAh[128 * 32], sAl[128 * 32];
    __shared__ __align__(16) _Float16 sBh[128 * 32], sBl[128 * 32];
    const int tid = threadIdx.x;
    const int w = tid >> 6, lane = tid & 63;
    const int wm = w >> 1, wn = w & 1;
    const int q = lane >> 4, l15 = lane & 15;
    const int bm = blockIdx.y, bn = blockIdx.x;
    f32x4 acc[4][4] = {};
    const int ksteps = K >> 5;
    for (int kt = 0; kt < ksteps; ++kt) {
        __syncthreads();
        const int kcol = kt << 5;
        stage_split(A, (long)bm * 128, K, kcol, sAh, sAl, 128, tid);
        stage_split(B, (long)bn * 128, K, kcol, sBh, sBl, 128, tid);
        __syncthreads();
        f16x8 aH[4], aL[4];
#pragma unroll
        for (int tm = 0; tm < 4; ++tm) {
            const int row = wm * 64 + tm * 16 + l15;
            aH[tm] = *(const f16x8*)&sAh[row * 32 + q * 8];
            aL[tm] = *(const f16x8*)&sAl[row * 32 + q * 8];
        }
#pragma unroll
        for (int tn = 0; tn < 4; ++tn) {
            const int rowb = wn * 64 + tn * 16 + l15;
            const f16x8 bH = *(const f16x8*)&sBh[rowb * 32 + q * 8];
            const f16x8 bL = *(const f16x8*)&sBl[rowb * 32 + q * 8];
#pragma unroll
            for (int tm = 0; tm < 4; ++tm) {
                acc[tm][tn] = __builtin_amdgcn_mfma_f32_16x16x32_f16(aH[tm], bH, acc[tm][tn], 0, 0, 0);
                acc[tm][tn] = __builtin_amdgcn_mfma_f32_16x16x32_f16(aH[tm], bL, acc[tm][tn], 0, 0, 0);
                acc[tm][tn] = __builtin_amdgcn_mfma_f32_16x16x32_f16(aL[tm], bH, acc[tm][tn], 0, 0, 0);
            }
        }
    }
    float bv[4];
#pragma unroll
    for (int tn = 0; tn < 4; ++tn) bv[tn] = bias[bn * 128 + wn * 64 + tn * 16 + l15];
#pragma unroll
    for (int tm = 0; tm < 4; ++tm) {
        const int m0 = bm * 128 + wm * 64 + tm * 16 + q * 4;
#pragma unroll
        for (int tn = 0; tn < 4; ++tn) {
            const int n = bn * 128 + wn * 64 + tn * 16 + l15;
#pragma unroll
            for (int r = 0; r < 4; ++r)
                C[(long)(m0 + r) * N + n] = acc[tm][tn][r] + bv[tn];
        }
    }
}

// ---------------------------------------------------------------------------
// Dendrite GEMM + abs-max gating epilogue, one layer per launch.
// dend[b, n] = ctx[b,:] . seg[n,:], n = h*10 + s, 20480 rows per layer.
// Tile 128(b) x 160(n) = 16 h-groups x 10 segments exactly.
// Epilogue: acc -> LDS (2 chunks of 64 b-rows), per (b,h) pick
// dend[argmax_s |dend|] with strict > (first occurrence, = jnp.argmax),
// write sigmoid to gates[b][h] fp32.
// ---------------------------------------------------------------------------
__global__ __launch_bounds__(256) void dend_gemm(const float* __restrict__ ctx,
                                                 const float* __restrict__ seg,
                                                 float* __restrict__ gates) {
    __shared__ __align__(16) char smem[64 * 164 * 4];  // 41984 B
    _Float16* sAh = (_Float16*)smem;                    //  8192 B
    _Float16* sAl = (_Float16*)(smem + 8192);           //  8192 B
    _Float16* sBh = (_Float16*)(smem + 16384);          // 10240 B
    _Float16* sBl = (_Float16*)(smem + 26624);          // 10240 B
    float* Cred = (float*)smem;                         // [64][164] (union)
    const int tid = threadIdx.x;
    const int w = tid >> 6, lane = tid & 63;
    const int wm = w >> 1, wn = w & 1;
    const int q = lane >> 4, l15 = lane & 15;
    const int bm = blockIdx.y, bn = blockIdx.x;
    f32x4 acc[4][5] = {};
    for (int kt = 0; kt < 32; ++kt) {
        __syncthreads();
        const int kcol = kt << 5;
        stage_split(ctx, (long)bm * 128, 1024, kcol, sAh, sAl, 128, tid);
        stage_split(seg, (long)bn * 160, 1024, kcol, sBh, sBl, 160, tid);
        __syncthreads();
        f16x8 aH[4], aL[4];
#pragma unroll
        for (int tm = 0; tm < 4; ++tm) {
            const int row = wm * 64 + tm * 16 + l15;
            aH[tm] = *(const f16x8*)&sAh[row * 32 + q * 8];
            aL[tm] = *(const f16x8*)&sAl[row * 32 + q * 8];
        }
#pragma unroll
        for (int tn = 0; tn < 5; ++tn) {
            const int rowb = wn * 80 + tn * 16 + l15;
            const f16x8 bH = *(const f16x8*)&sBh[rowb * 32 + q * 8];
            const f16x8 bL = *(const f16x8*)&sBl[rowb * 32 + q * 8];
#pragma unroll
            for (int tm = 0; tm < 4; ++tm) {
                acc[tm][tn] = __builtin_amdgcn_mfma_f32_16x16x32_f16(aH[tm], bH, acc[tm][tn], 0, 0, 0);
                acc[tm][tn] = __builtin_amdgcn_mfma_f32_16x16x32_f16(aH[tm], bL, acc[tm][tn], 0, 0, 0);
                acc[tm][tn] = __builtin_amdgcn_mfma_f32_16x16x32_f16(aL[tm], bH, acc[tm][tn], 0, 0, 0);
            }
        }
    }
    // epilogue: two 64-row chunks through LDS
    for (int c = 0; c < 2; ++c) {
        __syncthreads();  // previous chunk's reads (or staging) done
        if (wm == c) {
#pragma unroll
            for (int tm = 0; tm < 4; ++tm)
#pragma unroll
                for (int tn = 0; tn < 5; ++tn)
#pragma unroll
                    for (int r = 0; r < 4; ++r)
                        Cred[(tm * 16 + q * 4 + r) * 164 + wn * 80 + tn * 16 + l15] =
                            acc[tm][tn][r];
        }
        __syncthreads();
        for (int p = tid; p < 1024; p += 256) {
            const int bb = p >> 4, hh = p & 15;
            const float* d = &Cred[bb * 164 + hh * 10];
            float best = d[0], ba = fabsf(d[0]);
#pragma unroll
            for (int s = 1; s < 10; ++s) {
                const float v = d[s], a = fabsf(v);
                if (a > ba) { ba = a; best = v; }  // strict >: first occurrence
            }
            const float gate = 1.f / (1.f + expf(-best));
            const int bg = bm * 128 + c * 64 + bb;
            const int h = bn * 16 + hh;
            gates[(long)bg * 2048 + h] = gate;
        }
    }
}

// ---------------------------------------------------------------------------
// KWinners: per row, v = y * gate (fp32); exact 102nd-largest via 4-round
// radix select on order-preserving uint keys; keep v where key >= kth
// (reproduces jnp `x >= kth` incl. ties); h out as fp32.
// ---------------------------------------------------------------------------
__global__ __launch_bounds__(256) void kwinners_kernel(const float* __restrict__ y,
                                                       const float* __restrict__ g,
                                                       float* __restrict__ h) {
    __shared__ unsigned hist[256];
    __shared__ unsigned scan[257];
    __shared__ int sb, srank;
    const int tid = threadIdx.x;
    const long base = (long)blockIdx.x * 2048;
    float v[8];
    unsigned u[8];
#pragma unroll
    for (int j = 0; j < 8; ++j) {
        const int i = j * 256 + tid;
        const float val = y[base + i] * g[base + i];
        v[j] = val;
        const unsigned b = __float_as_uint(val);
        u[j] = b ^ (unsigned)((((int)b) >> 31) | 0x80000000);  // monotone map
    }
    unsigned prefix = 0, pmask = 0;
    int rank = 102;
    for (int round = 0; round < 4; ++round) {
        const int shift = 24 - (round << 3);
        hist[tid] = 0;
        if (tid == 0) scan[256] = 0;
        __syncthreads();
#pragma unroll
        for (int j = 0; j < 8; ++j)
            if ((u[j] & pmask) == prefix) atomicAdd(&hist[(u[j] >> shift) & 255], 1u);
        __syncthreads();
        scan[tid] = hist[tid];
        __syncthreads();
        for (int off = 1; off < 256; off <<= 1) {  // inclusive suffix sum
            const unsigned t = scan[tid] + ((tid + off < 256) ? scan[tid + off] : 0u);
            __syncthreads();
            scan[tid] = t;
            __syncthreads();
        }
        if (scan[tid] >= (unsigned)rank && scan[tid + 1] < (unsigned)rank) {
            sb = tid;
            srank = rank - (int)scan[tid + 1];
        }
        __syncthreads();
        prefix |= ((unsigned)sb) << shift;
        pmask |= 255u << shift;
        rank = srank;
        __syncthreads();
    }
#pragma unroll
    for (int j = 0; j < 8; ++j) {
        const int i = j * 256 + tid;
        h[base + i] = (u[j] >= prefix) ? v[j] : 0.f;
    }
}

// ---------------------------------------------------------------------------
extern "C" void kernel_launch(void* const* d_in, const int* in_sizes, int n_in,
                              void* d_out, int out_size, void* d_ws, size_t ws_size,
                              hipStream_t stream) {
    const float* x    = (const float*)d_in[0];
    const float* ctx  = (const float*)d_in[1];
    const float* w1   = (const float*)d_in[2];
    const float* b1   = (const float*)d_in[3];
    const float* seg1 = (const float*)d_in[4];
    const float* w2   = (const float*)d_in[5];
    const float* b2   = (const float*)d_in[6];
    const float* seg2 = (const float*)d_in[7];
    const float* wo   = (const float*)d_in[8];
    const float* bo   = (const float*)d_in[9];

    const long N_Y = 4096L * 2048;  // [B][HIDDEN]

    char* p = (char*)d_ws;
    auto take = [&](size_t bytes) {
        char* r = p;
        p += (bytes + 255) & ~(size_t)255;
        return r;
    };
    float* gates = (float*)take(N_Y * 4);  // 32 MB, reused for both layers
    float* yb    = (float*)take(N_Y * 4);  // 32 MB
    float* hbuf  = (float*)take(N_Y * 4);  // 32 MB
    (void)ws_size;

    // layer 1
    dend_gemm<<<dim3(128, 32), dim3(256), 0, stream>>>(ctx, seg1, gates);
    gemm_split<<<dim3(16, 32), dim3(256), 0, stream>>>(x, w1, b1, yb, 2048, 1024);
    kwinners_kernel<<<dim3(4096), dim3(256), 0, stream>>>(yb, gates, hbuf);
    // layer 2 (gates buffer reused; stream order serializes with kwinners)
    dend_gemm<<<dim3(128, 32), dim3(256), 0, stream>>>(ctx, seg2, gates);
    gemm_split<<<dim3(16, 32), dim3(256), 0, stream>>>(hbuf, w2, b2, yb, 2048, 2048);
    kwinners_kernel<<<dim3(4096), dim3(256), 0, stream>>>(yb, gates, hbuf);
    // output layer
    gemm_split<<<dim3(8, 32), dim3(256), 0, stream>>>(hbuf, wo, bo, (float*)d_out,
                                                      1024, 2048);
}

// Round 3
// 1389.859 us; speedup vs baseline: 1.8447x; 1.8447x over previous
//
#include <hip/hip_runtime.h>

// ---------------------------------------------------------------------------
// DendriticMLP on MI355X — round 3.
// f16 hi/lo split GEMMs (3-term MFMA, ~2^-22 error) as round 2, restructured:
//  - A-operands pre-split to f16 planes in ws; staged via global_load_lds DMA
//  - B-operands split in-kernel with next-K register prefetch
//  - XOR-swizzled LDS layout (2-way max bank aliasing = free)
//  - 40960 B LDS -> 4 blocks/CU
// Workspace: exactly 96 MB (proven safe), regions time-multiplexed.
// ---------------------------------------------------------------------------

#define AS1 __attribute__((address_space(1)))
#define AS3 __attribute__((address_space(3)))

typedef _Float16 f16x8 __attribute__((ext_vector_type(8)));
typedef _Float16 f16x4 __attribute__((ext_vector_type(4)));
typedef float    f32x4 __attribute__((ext_vector_type(4)));

// swizzled halfword offset of logical chunk q (0..3) in row of a [rows][32]
// f16 tile: physical chunk = q ^ ((row>>1)&3) -> frag reads are 2-way max.
__device__ __forceinline__ int swz(int row, int q) {
    return row * 32 + ((q ^ ((row >> 1) & 3)) << 3);
}

// ---------------------------------------------------------------------------
// split: fp32 -> f16 hi + f16 lo planes (a ~= hi+lo, err ~2^-22 |a|)
// ---------------------------------------------------------------------------
__global__ __launch_bounds__(256) void split_kernel(const float* __restrict__ s,
                                                    _Float16* __restrict__ hi,
                                                    _Float16* __restrict__ lo, int n4) {
    int i = blockIdx.x * 256 + threadIdx.x;
    if (i >= n4) return;
    float4 a = ((const float4*)s)[i];
    f16x4 h, l;
    h.x = (_Float16)a.x; l.x = (_Float16)(a.x - (float)h.x);
    h.y = (_Float16)a.y; l.y = (_Float16)(a.y - (float)h.y);
    h.z = (_Float16)a.z; l.z = (_Float16)(a.z - (float)h.z);
    h.w = (_Float16)a.w; l.w = (_Float16)(a.w - (float)h.w);
    ((f16x4*)hi)[i] = h;
    ((f16x4*)lo)[i] = l;
}

// DMA one 128x32 f16 plane tile into swizzled LDS. Source addresses are
// permuted per-lane; LDS dest is wave-uniform base + lane*16 (HW semantics).
__device__ __forceinline__ void dma_plane(const _Float16* __restrict__ g, long row0,
                                          int ldHalf, int kcol, _Float16* lds, int tid) {
#pragma unroll
    for (int rep = 0; rep < 2; ++rep) {
        const int s = tid + rep * 256;           // physical 16B slot, 512 total
        const int row = s >> 2, cp = s & 3;
        const int src = cp ^ ((row >> 1) & 3);   // logical chunk at this slot
        const _Float16* gp = g + (row0 + row) * (long)ldHalf + kcol + src * 8;
        __builtin_amdgcn_global_load_lds((const AS1 void*)gp,
                                         (AS3 void*)(lds + ((s & ~63) << 3)), 16, 0, 0);
    }
}

// ---------------------------------------------------------------------------
// Split GEMM: C[M,N] = A[M,K] @ B[N,K]^T + bias[N]; A as f16 hi/lo planes
// (DMA-staged), B fp32 (register-prefetched, split in-kernel). 128x128 tile,
// 4 waves 2x2, 4x4 of 16x16x32_f16 MFMA, 3 MFMAs per pair (hh+hl+lh).
// ---------------------------------------------------------------------------
__global__ __launch_bounds__(256) void gemm_split(
    const _Float16* __restrict__ AH, const _Float16* __restrict__ AL,
    const float* __restrict__ B, const float* __restrict__ bias,
    float* __restrict__ C, int N, int K) {
    __shared__ __align__(16) _Float16 sAh[128 * 32], sAl[128 * 32];
    __shared__ __align__(16) _Float16 sBh[128 * 32], sBl[128 * 32];
    const int tid = threadIdx.x;
    const int w = tid >> 6, lane = tid & 63;
    const int wm = w >> 1, wn = w & 1;
    const int q = lane >> 4, l15 = lane & 15;
    const int bm = blockIdx.y, bn = blockIdx.x;
    const long brow0 = (long)bn * 128;
    f32x4 acc[4][4] = {};
    float4 pre[4];
    auto loadB = [&](int kt) {
#pragma unroll
        for (int j = 0; j < 4; ++j) {
            const int c = tid + j * 256;          // 1024 half-chunks
            const int row = c >> 3, hc = c & 7;
            pre[j] = *(const float4*)(B + (brow0 + row) * (long)K + (kt << 5) + (hc << 2));
        }
    };
    loadB(0);
    const int ksteps = K >> 5;
    for (int kt = 0; kt < ksteps; ++kt) {
        const int kcol = kt << 5;
        dma_plane(AH, (long)bm * 128, K, kcol, sAh, tid);
        dma_plane(AL, (long)bm * 128, K, kcol, sAl, tid);
#pragma unroll
        for (int j = 0; j < 4; ++j) {
            const int c = tid + j * 256;
            const int row = c >> 3, hc = c & 7;
            const float4 v = pre[j];
            f16x4 h, l;
            h.x = (_Float16)v.x; l.x = (_Float16)(v.x - (float)h.x);
            h.y = (_Float16)v.y; l.y = (_Float16)(v.y - (float)h.y);
            h.z = (_Float16)v.z; l.z = (_Float16)(v.z - (float)h.z);
            h.w = (_Float16)v.w; l.w = (_Float16)(v.w - (float)h.w);
            const int off = row * 32 + (((hc >> 1) ^ ((row >> 1) & 3)) << 3) + ((hc & 1) << 2);
            *(f16x4*)(sBh + off) = h;
            *(f16x4*)(sBl + off) = l;
        }
        if (kt + 1 < ksteps) loadB(kt + 1);   // overlaps with MFMA below
        __syncthreads();                       // drains DMA + ds_writes
        f16x8 aH[4], aL[4];
#pragma unroll
        for (int tm = 0; tm < 4; ++tm) {
            const int row = wm * 64 + tm * 16 + l15;
            aH[tm] = *(const f16x8*)&sAh[swz(row, q)];
            aL[tm] = *(const f16x8*)&sAl[swz(row, q)];
        }
#pragma unroll
        for (int tn = 0; tn < 4; ++tn) {
            const int rowb = wn * 64 + tn * 16 + l15;
            const f16x8 bH = *(const f16x8*)&sBh[swz(rowb, q)];
            const f16x8 bL = *(const f16x8*)&sBl[swz(rowb, q)];
#pragma unroll
            for (int tm = 0; tm < 4; ++tm) {
                acc[tm][tn] = __builtin_amdgcn_mfma_f32_16x16x32_f16(aH[tm], bH, acc[tm][tn], 0, 0, 0);
                acc[tm][tn] = __builtin_amdgcn_mfma_f32_16x16x32_f16(aH[tm], bL, acc[tm][tn], 0, 0, 0);
                acc[tm][tn] = __builtin_amdgcn_mfma_f32_16x16x32_f16(aL[tm], bH, acc[tm][tn], 0, 0, 0);
            }
        }
        __syncthreads();                       // frag reads done before overwrite
    }
    float bv[4];
#pragma unroll
    for (int tn = 0; tn < 4; ++tn) bv[tn] = bias[bn * 128 + wn * 64 + tn * 16 + l15];
#pragma unroll
    for (int tm = 0; tm < 4; ++tm) {
        const int m0 = bm * 128 + wm * 64 + tm * 16 + q * 4;
#pragma unroll
        for (int tn = 0; tn < 4; ++tn) {
            const int n = bn * 128 + wn * 64 + tn * 16 + l15;
#pragma unroll
            for (int r = 0; r < 4; ++r)
                C[(long)(m0 + r) * N + n] = acc[tm][tn][r] + bv[tn];
        }
    }
}

// ---------------------------------------------------------------------------
// Dendrite GEMM + abs-max gating epilogue (one layer per launch).
// dend[b, n] = ctx[b,:].seg[n,:], n = h*10+s, 20480 rows. Tile 128(b)x160(n)
// = 16 h-groups x 10 segments. ctx as planes (DMA), seg fp32 (prefetch+split).
// Epilogue: acc -> LDS [64][160], argmax_s |dend| (strict >, = jnp.argmax),
// gates[b][h] = sigmoid(selected), fp32.
// ---------------------------------------------------------------------------
__global__ __launch_bounds__(256) void dend_gemm(const _Float16* __restrict__ AH,
                                                 const _Float16* __restrict__ AL,
                                                 const float* __restrict__ seg,
                                                 float* __restrict__ gates) {
    __shared__ __align__(16) char smem[40960];
    _Float16* sAh = (_Float16*)smem;            //  8192 B
    _Float16* sAl = (_Float16*)(smem + 8192);   //  8192 B
    _Float16* sBh = (_Float16*)(smem + 16384);  // 10240 B (160x32)
    _Float16* sBl = (_Float16*)(smem + 26624);  // 10240 B
    float* Cred = (float*)smem;                 // [64][160] union, 40960 B
    const int tid = threadIdx.x;
    const int w = tid >> 6, lane = tid & 63;
    const int wm = w >> 1, wn = w & 1;
    const int q = lane >> 4, l15 = lane & 15;
    const int bm = blockIdx.y, bn = blockIdx.x;
    const long brow0 = (long)bn * 160;
    f32x4 acc[4][5] = {};
    float4 pre[5];
    auto loadB = [&](int kt) {
#pragma unroll
        for (int j = 0; j < 5; ++j) {
            const int c = tid + j * 256;          // 1280 half-chunks
            const int row = c >> 3, hc = c & 7;
            pre[j] = *(const float4*)(seg + (brow0 + row) * 1024L + (kt << 5) + (hc << 2));
        }
    };
    loadB(0);
    for (int kt = 0; kt < 32; ++kt) {
        const int kcol = kt << 5;
        dma_plane(AH, (long)bm * 128, 1024, kcol, sAh, tid);
        dma_plane(AL, (long)bm * 128, 1024, kcol, sAl, tid);
#pragma unroll
        for (int j = 0; j < 5; ++j) {
            const int c = tid + j * 256;
            const int row = c >> 3, hc = c & 7;
            const float4 v = pre[j];
            f16x4 h, l;
            h.x = (_Float16)v.x; l.x = (_Float16)(v.x - (float)h.x);
            h.y = (_Float16)v.y; l.y = (_Float16)(v.y - (float)h.y);
            h.z = (_Float16)v.z; l.z = (_Float16)(v.z - (float)h.z);
            h.w = (_Float16)v.w; l.w = (_Float16)(v.w - (float)h.w);
            const int off = row * 32 + (((hc >> 1) ^ ((row >> 1) & 3)) << 3) + ((hc & 1) << 2);
            *(f16x4*)(sBh + off) = h;
            *(f16x4*)(sBl + off) = l;
        }
        if (kt < 31) loadB(kt + 1);
        __syncthreads();
        f16x8 aH[4], aL[4];
#pragma unroll
        for (int tm = 0; tm < 4; ++tm) {
            const int row = wm * 64 + tm * 16 + l15;
            aH[tm] = *(const f16x8*)&sAh[swz(row, q)];
            aL[tm] = *(const f16x8*)&sAl[swz(row, q)];
        }
#pragma unroll
        for (int tn = 0; tn < 5; ++tn) {
            const int rowb = wn * 80 + tn * 16 + l15;
            const f16x8 bH = *(const f16x8*)&sBh[swz(rowb, q)];
            const f16x8 bL = *(const f16x8*)&sBl[swz(rowb, q)];
#pragma unroll
            for (int tm = 0; tm < 4; ++tm) {
                acc[tm][tn] = __builtin_amdgcn_mfma_f32_16x16x32_f16(aH[tm], bH, acc[tm][tn], 0, 0, 0);
                acc[tm][tn] = __builtin_amdgcn_mfma_f32_16x16x32_f16(aH[tm], bL, acc[tm][tn], 0, 0, 0);
                acc[tm][tn] = __builtin_amdgcn_mfma_f32_16x16x32_f16(aL[tm], bH, acc[tm][tn], 0, 0, 0);
            }
        }
        __syncthreads();
    }
    // epilogue: two 64-row chunks through LDS; [64][160] has conflict-free
    // scan reads (hh*10 mod 32 distinct over hh=0..15)
    for (int c = 0; c < 2; ++c) {
        __syncthreads();
        if (wm == c) {
#pragma unroll
            for (int tm = 0; tm < 4; ++tm)
#pragma unroll
                for (int tn = 0; tn < 5; ++tn)
#pragma unroll
                    for (int r = 0; r < 4; ++r)
                        Cred[(tm * 16 + q * 4 + r) * 160 + wn * 80 + tn * 16 + l15] =
                            acc[tm][tn][r];
        }
        __syncthreads();
        for (int p = tid; p < 1024; p += 256) {
            const int bb = p >> 4, hh = p & 15;
            const float* d = &Cred[bb * 160 + hh * 10];
            float best = d[0], ba = fabsf(d[0]);
#pragma unroll
            for (int s = 1; s < 10; ++s) {
                const float v = d[s], a = fabsf(v);
                if (a > ba) { ba = a; best = v; }  // strict >: first occurrence
            }
            const float gate = 1.f / (1.f + expf(-best));
            const int bg = bm * 128 + c * 64 + bb;
            const int h = bn * 16 + hh;
            gates[(long)bg * 2048 + h] = gate;
        }
    }
}

// ---------------------------------------------------------------------------
// KWinners: v = y*gate (fp32); exact 102nd-largest via radix select on
// order-preserving uint keys; keep where key >= kth (jnp `x >= kth` ties);
// emit h as f16 hi/lo planes (feeds next GEMM's A-DMA path).
// ---------------------------------------------------------------------------
__global__ __launch_bounds__(256) void kwinners_kernel(const float* __restrict__ y,
                                                       const float* __restrict__ g,
                                                       _Float16* __restrict__ hH,
                                                       _Float16* __restrict__ hL) {
    __shared__ unsigned hist[256];
    __shared__ unsigned scan[257];
    __shared__ int sb, srank;
    const int tid = threadIdx.x;
    const long base = (long)blockIdx.x * 2048;
    float v[8];
    unsigned u[8];
#pragma unroll
    for (int j = 0; j < 8; ++j) {
        const int i = j * 256 + tid;
        const float val = y[base + i] * g[base + i];
        v[j] = val;
        const unsigned b = __float_as_uint(val);
        u[j] = b ^ (unsigned)((((int)b) >> 31) | 0x80000000);  // monotone map
    }
    unsigned prefix = 0, pmask = 0;
    int rank = 102;
    for (int round = 0; round < 4; ++round) {
        const int shift = 24 - (round << 3);
        hist[tid] = 0;
        if (tid == 0) scan[256] = 0;
        __syncthreads();
#pragma unroll
        for (int j = 0; j < 8; ++j)
            if ((u[j] & pmask) == prefix) atomicAdd(&hist[(u[j] >> shift) & 255], 1u);
        __syncthreads();
        scan[tid] = hist[tid];
        __syncthreads();
        for (int off = 1; off < 256; off <<= 1) {  // inclusive suffix sum
            const unsigned t = scan[tid] + ((tid + off < 256) ? scan[tid + off] : 0u);
            __syncthreads();
            scan[tid] = t;
            __syncthreads();
        }
        if (scan[tid] >= (unsigned)rank && scan[tid + 1] < (unsigned)rank) {
            sb = tid;
            srank = rank - (int)scan[tid + 1];
        }
        __syncthreads();
        prefix |= ((unsigned)sb) << shift;
        pmask |= 255u << shift;
        rank = srank;
        __syncthreads();
    }
#pragma unroll
    for (int j = 0; j < 8; ++j) {
        const int i = j * 256 + tid;
        const float hv = (u[j] >= prefix) ? v[j] : 0.f;
        const _Float16 hi = (_Float16)hv;
        hH[base + i] = hi;
        hL[base + i] = (_Float16)(hv - (float)hi);
    }
}

// ---------------------------------------------------------------------------
extern "C" void kernel_launch(void* const* d_in, const int* in_sizes, int n_in,
                              void* d_out, int out_size, void* d_ws, size_t ws_size,
                              hipStream_t stream) {
    const float* x    = (const float*)d_in[0];
    const float* ctx  = (const float*)d_in[1];
    const float* w1   = (const float*)d_in[2];
    const float* b1   = (const float*)d_in[3];
    const float* seg1 = (const float*)d_in[4];
    const float* w2   = (const float*)d_in[5];
    const float* b2   = (const float*)d_in[6];
    const float* seg2 = (const float*)d_in[7];
    const float* wo   = (const float*)d_in[8];
    const float* bo   = (const float*)d_in[9];

    // 96 MB workspace (proven safe), three 32 MB regions, time-multiplexed:
    // r0: gates (fp32, both layers sequentially)
    // r1: ctx hi/lo planes (16 MB)  -> y (fp32 32 MB)  -> ctx planes -> y
    // r2: x hi/lo planes (16 MB)    -> h hi/lo planes (32 MB, per layer)
    char* base = (char*)d_ws;
    float*    gates = (float*)base;
    char*     r1    = base + (32L << 20);
    _Float16* ctxH  = (_Float16*)r1;
    _Float16* ctxL  = (_Float16*)(r1 + (8L << 20));
    float*    yb    = (float*)r1;
    char*     r2    = base + (64L << 20);
    _Float16* xH    = (_Float16*)r2;
    _Float16* xL    = (_Float16*)(r2 + (8L << 20));
    _Float16* hH    = (_Float16*)r2;
    _Float16* hL    = (_Float16*)(r2 + (16L << 20));
    (void)ws_size;

    const int n4_ctx = (4096 * 1024) / 4;  // 1M float4 -> 4096 blocks

    // layer 1
    split_kernel<<<dim3(4096), dim3(256), 0, stream>>>(ctx, ctxH, ctxL, n4_ctx);
    split_kernel<<<dim3(4096), dim3(256), 0, stream>>>(x, xH, xL, n4_ctx);
    dend_gemm<<<dim3(128, 32), dim3(256), 0, stream>>>(ctxH, ctxL, seg1, gates);
    gemm_split<<<dim3(16, 32), dim3(256), 0, stream>>>(xH, xL, w1, b1, yb, 2048, 1024);
    kwinners_kernel<<<dim3(4096), dim3(256), 0, stream>>>(yb, gates, hH, hL);
    // layer 2 (re-split ctx: its region was clobbered by y)
    split_kernel<<<dim3(4096), dim3(256), 0, stream>>>(ctx, ctxH, ctxL, n4_ctx);
    dend_gemm<<<dim3(128, 32), dim3(256), 0, stream>>>(ctxH, ctxL, seg2, gates);
    gemm_split<<<dim3(16, 32), dim3(256), 0, stream>>>(hH, hL, w2, b2, yb, 2048, 2048);
    kwinners_kernel<<<dim3(4096), dim3(256), 0, stream>>>(yb, gates, hH, hL);
    // output layer
    gemm_split<<<dim3(8, 32), dim3(256), 0, stream>>>(hH, hL, wo, bo, (float*)d_out,
                                                      1024, 2048);
}